// Round 6
// baseline (444.275 us; speedup 1.0000x reference)
//
#include <hip/hip_runtime.h>

namespace {

constexpr int L = 10000;   // links
constexpr int F = 8;       // input features
constexpr int H = 64;      // hidden size

typedef __bf16 bf16x8 __attribute__((ext_vector_type(8)));
typedef float  f32x4  __attribute__((ext_vector_type(4)));

constexpr int JPB = 16;            // links per block (full 64B line in j)
constexpr int XH_LINK = 64 * 33 + 1;   // 2113 words: i-stride 33, jl-stride 2113
                                        // -> A-frag reads ~2-way, epilogue ~4-way

__device__ __forceinline__ float fsigmoid(float x) {
    return 1.0f / (1.0f + __expf(-x));
}
__device__ __forceinline__ float ftanh(float x) {
    return 2.0f / (1.0f + __expf(-2.0f * x)) - 1.0f;
}

// One wave per link. MFMA 16x16x32 bf16.
// A-frag: lane holds A[row=lane&15][k=(lane>>4)*8+e]
// B-frag: lane holds B[k=(lane>>4)*8+e][col=lane&15]
// D: col=lane&15, row=(lane>>4)*4+reg   [guide-verified m89]
__global__ __launch_bounds__(1024, 4)
void gcrnn_mfma(const float* __restrict__ hidden, const float* __restrict__ xin,
                const float* __restrict__ Wrh, const float* __restrict__ Brh,
                const float* __restrict__ Wri, const float* __restrict__ Bri,
                const float* __restrict__ Wuh, const float* __restrict__ Buh,
                const float* __restrict__ Wui, const float* __restrict__ Bui,
                const float* __restrict__ Wnh, const float* __restrict__ Bnh,
                const float* __restrict__ Wni, const float* __restrict__ Bni,
                float* __restrict__ out)
{
    // bijective XCD-chunked swizzle over 625 workgroups (16 links each)
    constexpr int NWG = L / JPB;               // 625
    constexpr int q = NWG / 8, r = NWG % 8;    // 78, 1
    const int orig = blockIdx.x;
    const int xcd = orig & 7, idx = orig >> 3;
    const int wg = (xcd < r ? xcd * (q + 1) : r * (q + 1) + (xcd - r) * q) + idx;
    const int j0 = wg * JPB;

    __shared__ float sXh[JPB * XH_LINK];   // 135 KB; doubles as out staging
    __shared__ float sB[4 * JPB * 64];     // 16 KB (R/U biases pre-combined)

    const int tb = threadIdx.x;

    // ================= cooperative staging: every global read = full 64B line
    {
        const int jl = tb & 15;
        const int rq = tb >> 4;            // 0..63
        // Xh rows (b=c, i=rq): 16 lanes span j0..j0+15 = one line
#pragma unroll
        for (int c = 0; c < 32; ++c) {
            sXh[jl * XH_LINK + rq * 33 + c] =
                hidden[(size_t)(c * 64 + rq) * L + j0 + jl];
        }
        // biases (col = rq), R/U pre-combined
        const size_t o = (size_t)rq * L + j0 + jl;
        sB[0 * JPB * 64 + jl * 64 + rq] = Brh[o] + Bri[o];
        sB[1 * JPB * 64 + jl * 64 + rq] = Buh[o] + Bui[o];
        sB[2 * JPB * 64 + jl * 64 + rq] = Bnh[o];
        sB[3 * JPB * 64 + jl * 64 + rq] = Bni[o];
    }
    __syncthreads();

    // ================= per-wave per-link MFMA ================================
    const int lane = tb & 63;
    const int wv   = tb >> 6;              // wave owns link wv (0..15)
    const int j    = j0 + wv;
    const int lc   = lane & 15;
    const int grp  = lane >> 4;

    // A fragments from LDS
    bf16x8 aH[2][2];
    bf16x8 aI[2];
#pragma unroll
    for (int m = 0; m < 2; ++m) {
        const int b_ = m * 16 + lc;
#pragma unroll
        for (int ks = 0; ks < 2; ++ks)
#pragma unroll
            for (int e = 0; e < 8; ++e)
                aH[m][ks][e] = (__bf16)sXh[wv * XH_LINK + (ks * 32 + grp * 8 + e) * 33 + b_];
        // Xi direct from global (10 MB, L2/L3-resident), K-padded to 32
        const size_t ibase = (size_t)b_ * F * L + j;
#pragma unroll
        for (int e = 0; e < 8; ++e) {
            float v = (grp == 0) ? xin[ibase + (size_t)e * L] : 0.0f;
            aI[m][e] = (__bf16)v;
        }
    }

    const float* WR = Wrh + (size_t)j * H * H;
    const float* WU = Wuh + (size_t)j * H * H;
    const float* WN = Wnh + (size_t)j * H * H;
    const float* IR = Wri + (size_t)j * F * H;
    const float* IU = Wui + (size_t)j * F * H;
    const float* IN = Wni + (size_t)j * F * H;

#pragma unroll
    for (int n = 0; n < 4; ++n) {
        const int col = n * 16 + lc;

        // B fragments straight from global f32 (4 full 64B lines per instr,
        // each weight line fetched exactly once)
        bf16x8 bR[2], bU[2], bN[2];
#pragma unroll
        for (int ks = 0; ks < 2; ++ks)
#pragma unroll
            for (int e = 0; e < 8; ++e) {
                const int i = ks * 32 + grp * 8 + e;
                bR[ks][e] = (__bf16)WR[i * H + col];
                bU[ks][e] = (__bf16)WU[i * H + col];
                bN[ks][e] = (__bf16)WN[i * H + col];
            }
        bf16x8 iR, iU, iN;
#pragma unroll
        for (int e = 0; e < 8; ++e) {
            float vr = 0.0f, vu = 0.0f, vn = 0.0f;
            if (grp == 0) {
                vr = IR[e * H + col];
                vu = IU[e * H + col];
                vn = IN[e * H + col];
            }
            iR[e] = (__bf16)vr; iU[e] = (__bf16)vu; iN[e] = (__bf16)vn;
        }

        // biases from LDS (16 banks, broadcast across grp)
        const float biR  = sB[0 * JPB * 64 + wv * 64 + col];
        const float biU  = sB[1 * JPB * 64 + wv * 64 + col];
        const float biNH = sB[2 * JPB * 64 + wv * 64 + col];
        const float biNI = sB[3 * JPB * 64 + wv * 64 + col];

        // MFMAs: 4 gate accumulators x 2 m-tiles
        f32x4 accR[2], accU[2], accN[2], accNI[2];
#pragma unroll
        for (int m = 0; m < 2; ++m) {
            accR[m] = (f32x4){0.f, 0.f, 0.f, 0.f};
            accU[m] = (f32x4){0.f, 0.f, 0.f, 0.f};
            accN[m] = (f32x4){0.f, 0.f, 0.f, 0.f};
            accNI[m] = (f32x4){0.f, 0.f, 0.f, 0.f};
#pragma unroll
            for (int ks = 0; ks < 2; ++ks) {
                accR[m] = __builtin_amdgcn_mfma_f32_16x16x32_bf16(aH[m][ks], bR[ks], accR[m], 0, 0, 0);
                accU[m] = __builtin_amdgcn_mfma_f32_16x16x32_bf16(aH[m][ks], bU[ks], accU[m], 0, 0, 0);
                accN[m] = __builtin_amdgcn_mfma_f32_16x16x32_bf16(aH[m][ks], bN[ks], accN[m], 0, 0, 0);
            }
            accR[m]  = __builtin_amdgcn_mfma_f32_16x16x32_bf16(aI[m], iR, accR[m], 0, 0, 0);
            accU[m]  = __builtin_amdgcn_mfma_f32_16x16x32_bf16(aI[m], iU, accU[m], 0, 0, 0);
            accNI[m] = __builtin_amdgcn_mfma_f32_16x16x32_bf16(aI[m], iN, accNI[m], 0, 0, 0);
        }

        // epilogue: word (col*33+b_) is hidden(b_, i=col) on read and
        // out(b_, k=col) on write -- in-place, register-ordered, lane-private
#pragma unroll
        for (int m = 0; m < 2; ++m)
#pragma unroll
            for (int rr = 0; rr < 4; ++rr) {
                const int b_ = m * 16 + grp * 4 + rr;
                const int w = wv * XH_LINK + col * 33 + b_;
                const float h = sXh[w];
                const float rv = fsigmoid(accR[m][rr] + biR);
                const float uv = fsigmoid(accU[m][rr] + biU);
                const float nv = ftanh(rv * (accN[m][rr] + biNH) + accNI[m][rr] + biNI);
                sXh[w] = (1.0f - uv) * nv + uv * h;
            }
    }

    __syncthreads();

    // ================= cooperative writeout: every store = full 64B line ====
    {
        const int jl = tb & 15;
        const int rq = tb >> 4;            // k = rq
#pragma unroll
        for (int c = 0; c < 32; ++c) {     // b = c
            out[(size_t)(c * 64 + rq) * L + j0 + jl] =
                sXh[jl * XH_LINK + rq * 33 + c];
        }
    }
}

} // namespace

extern "C" void kernel_launch(void* const* d_in, const int* in_sizes, int n_in,
                              void* d_out, int out_size, void* d_ws, size_t ws_size,
                              hipStream_t stream) {
    const float* hidden = (const float*)d_in[0];
    const float* xin    = (const float*)d_in[1];
    const float* Wrh    = (const float*)d_in[2];
    const float* Brh    = (const float*)d_in[3];
    const float* Wri    = (const float*)d_in[4];
    const float* Bri    = (const float*)d_in[5];
    const float* Wuh    = (const float*)d_in[6];
    const float* Buh    = (const float*)d_in[7];
    const float* Wui    = (const float*)d_in[8];
    const float* Bui    = (const float*)d_in[9];
    const float* Wnh    = (const float*)d_in[10];
    const float* Bnh    = (const float*)d_in[11];
    const float* Wni    = (const float*)d_in[12];
    const float* Bni    = (const float*)d_in[13];
    float* out = (float*)d_out;

    gcrnn_mfma<<<L / JPB, 1024, 0, stream>>>(hidden, xin,
                                             Wrh, Brh, Wri, Bri,
                                             Wuh, Buh, Wui, Bui,
                                             Wnh, Bnh, Wni, Bni,
                                             out);
}